// Round 4
// baseline (276.127 us; speedup 1.0000x reference)
//
#include <hip/hip_runtime.h>

#define DD   128
#define KTOT 1024
#define BTOT 131072

typedef __attribute__((ext_vector_type(8))) short bfrag8;    // 8 bf16 (4 VGPR)
typedef __attribute__((ext_vector_type(16))) float facc16;   // 32x32 MFMA accumulator

__device__ __forceinline__ unsigned short bf16_rne(float x) {
    unsigned u = __builtin_bit_cast(unsigned, x);
    u += 0x7fffu + ((u >> 16) & 1u);
    return (unsigned short)(u >> 16);
}
__device__ __forceinline__ float bf16f(unsigned short h) {
    unsigned u = ((unsigned)h) << 16;
    return __builtin_bit_cast(float, u);
}
__device__ __forceinline__ void gload_lds16(const void* g, void* l) {
    __builtin_amdgcn_global_load_lds(
        (const __attribute__((address_space(1))) void*)g,
        (__attribute__((address_space(3))) void*)l, 16, 0, 0);
}

// ---- prep: one wave per code; Eh/El = bf16 split of (-2*w*e) ----
__global__ __launch_bounds__(256) void vq_prep(
    const float* __restrict__ E, const float* __restrict__ ema,
    unsigned* __restrict__ Eh32, unsigned* __restrict__ El32,
    float* __restrict__ alpha, float* __restrict__ beta)
{
    const int tid = threadIdx.x, lane = tid & 63, wid = tid >> 6;
    const int k = blockIdx.x * 4 + wid;
    const float2 e2 = *(const float2*)(E + (size_t)k * DD + lane * 2);
    double ss = (double)e2.x * e2.x + (double)e2.y * e2.y;
    #pragma unroll
    for (int off = 1; off < 64; off <<= 1) ss += __shfl_xor(ss, off);
    float w = ema[k];
    float tw = -2.0f * w;
    float v0 = tw * e2.x, v1 = tw * e2.y;
    unsigned short h0 = bf16_rne(v0), h1 = bf16_rne(v1);
    unsigned short l0 = bf16_rne(v0 - bf16f(h0)), l1 = bf16_rne(v1 - bf16f(h1));
    Eh32[k * 64 + lane] = (unsigned)h0 | ((unsigned)h1 << 16);
    El32[k * 64 + lane] = (unsigned)l0 | ((unsigned)l1 << 16);
    if (lane == 0) { alpha[k] = w; beta[k] = (float)((double)w * ss); }
}

// ---- main: 32x32x16 MFMA, seeded-C distances, swizzled LDS dbuf ----
__global__ __launch_bounds__(256, 2) void vq_mfma(
    const float* __restrict__ X, const float* __restrict__ E,
    const unsigned short* __restrict__ Eh, const unsigned short* __restrict__ El,
    const float* __restrict__ alpha, const float* __restrict__ beta,
    float* __restrict__ outZ, float* __restrict__ outIdx,
    double* __restrict__ lossAcc, int* __restrict__ refCount,
    int* __restrict__ refList, int refCap)
{
    __shared__ __align__(1024) char smem[33280];   // 2 x 16KB dbuf + 512B idx
    int* ldsIdx = (int*)(smem + 32768);

    const int tid = threadIdx.x, lane = tid & 63, wid = tid >> 6;
    const int col = lane & 31, g2 = lane >> 5, m15 = lane & 15;
    const int rb = blockIdx.x * 128 + wid * 32;

    // staging: wave stages rows [wid*8, wid*8+8) of h and l (2 calls each).
    // LDS slot tt of row c holds global chunk (tt ^ (c&15))  [involution]
    int soff[2], dofs[2];
    #pragma unroll
    for (int q = 0; q < 2; ++q) {
        int cb = wid * 8 + q * 4;
        int c = cb + (lane >> 4);
        soff[q] = c * 256 + ((m15 ^ (c & 15)) << 4);
        dofs[q] = cb * 256;
    }
    const char* EhB = (const char*)Eh;
    const char* ElB = (const char*)El;

    // prologue: stage tile 0 into buf 0
    #pragma unroll
    for (int q = 0; q < 2; ++q) {
        gload_lds16(EhB + soff[q], smem + dofs[q]);
        gload_lds16(ElB + soff[q], smem + 8192 + dofs[q]);
    }

    // A fragments: row = rb+col, k = s*16 + g2*8 + j; hi/lo bf16 split
    bfrag8 Ah[8], Al[8];
    float p = 0.f;
    const float* xr = X + (size_t)(rb + col) * DD + g2 * 8;
    #pragma unroll
    for (int s = 0; s < 8; ++s) {
        float4 v0 = *(const float4*)(xr + s * 16);
        float4 v1 = *(const float4*)(xr + s * 16 + 4);
        float xs8[8] = {v0.x, v0.y, v0.z, v0.w, v1.x, v1.y, v1.z, v1.w};
        #pragma unroll
        for (int j = 0; j < 8; ++j) {
            float x = xs8[j];
            p = fmaf(x, x, p);
            unsigned short h = bf16_rne(x);
            Ah[s][j] = (short)h;
            Al[s][j] = (short)bf16_rne(x - bf16f(h));
        }
    }
    p += __shfl_xor(p, 32);                  // full ||x||^2 of row rb+col
    float crs[16];
    #pragma unroll
    for (int r = 0; r < 16; ++r)
        crs[r] = __shfl(p, (r & 3) + 8 * (r >> 2) + 4 * g2);

    // swizzled ds_read offsets: slot ((2s+g2) ^ m15) of row 'col'
    int rof[8];
    #pragma unroll
    for (int s = 0; s < 8; ++s)
        rof[s] = col * 256 + ((((s << 1) | g2) ^ m15) << 4);

    float b1[16], b2[16];
    int   i1[16];
    #pragma unroll
    for (int r = 0; r < 16; ++r) { b1[r] = 3e38f; b2[r] = 3e38f; i1[r] = 0; }

    __syncthreads();                         // tile 0 staged

    int cur = 0;
    #pragma unroll 2
    for (int t = 0; t < 32; ++t) {
        if (t + 1 < 32) {                    // stage next tile
            const char* eh2 = EhB + (size_t)(t + 1) * 8192;
            const char* el2 = ElB + (size_t)(t + 1) * 8192;
            char* nb = smem + ((cur ^ 1) * 16384);
            #pragma unroll
            for (int q = 0; q < 2; ++q) {
                gload_lds16(eh2 + soff[q], nb + dofs[q]);
                gload_lds16(el2 + soff[q], nb + 8192 + dofs[q]);
            }
        }
        const int cb32 = t * 32;
        float av = alpha[cb32 + col], bv = beta[cb32 + col];
        facc16 acc0, acc1;
        #pragma unroll
        for (int r = 0; r < 16; ++r) { acc0[r] = fmaf(av, crs[r], bv); acc1[r] = 0.f; }

        const char* bb = smem + cur * 16384;
        #pragma unroll
        for (int s = 0; s < 8; ++s) {
            bfrag8 Bh = *(const bfrag8*)(bb + rof[s]);
            bfrag8 Bl = *(const bfrag8*)(bb + 8192 + rof[s]);
            acc0 = __builtin_amdgcn_mfma_f32_32x32x16_bf16(Ah[s], Bh, acc0, 0, 0, 0);
            acc1 = __builtin_amdgcn_mfma_f32_32x32x16_bf16(Ah[s], Bl, acc1, 0, 0, 0);
            acc1 = __builtin_amdgcn_mfma_f32_32x32x16_bf16(Al[s], Bh, acc1, 0, 0, 0);
        }

        #pragma unroll
        for (int r = 0; r < 16; ++r) {
            float dd = acc0[r] + acc1[r];    // seeded: dd IS the distance
            bool lt = dd < b1[r];
            b2[r] = fminf(b2[r], fmaxf(b1[r], dd));
            b1[r] = fminf(b1[r], dd);
            i1[r] = lt ? cb32 : i1[r];       // lane's code = base + col
        }
        __syncthreads();
        cur ^= 1;
    }

    // ---- cross-lane top-2 reduce over 32 columns (within g2 half) ----
    int code[16];
    #pragma unroll
    for (int r = 0; r < 16; ++r) code[r] = i1[r] + col;
    #pragma unroll
    for (int off = 1; off < 32; off <<= 1) {
        #pragma unroll
        for (int r = 0; r < 16; ++r) {
            float ob1 = __shfl_xor(b1[r], off);
            float ob2 = __shfl_xor(b2[r], off);
            int   oc  = __shfl_xor(code[r], off);
            bool better = (ob1 < b1[r]) || (ob1 == b1[r] && oc < code[r]);
            float nb2 = better ? fminf(ob2, b1[r]) : fminf(b2[r], ob1);
            b1[r]   = better ? ob1 : b1[r];
            code[r] = better ? oc  : code[r];
            b2[r]   = nb2;
        }
    }

    // ---- writers (col==0: lanes 0,32): idx, flags, loss = sum b1/w ----
    double lsum = 0.0;
    if (col == 0) {
        #pragma unroll
        for (int r = 0; r < 16; ++r) {
            int rl = (r & 3) + 8 * (r >> 2) + 4 * g2;
            int row = rb + rl;
            int bc = code[r];
            outIdx[row] = (float)bc;
            ldsIdx[wid * 32 + rl] = bc;
            lsum += (double)b1[r] / (double)alpha[bc];
            float thr = fmaf(4e-4f, b1[r], 2e-6f);
            if (b2[r] - b1[r] < thr) {
                int pz = atomicAdd(refCount, 1);
                if (pz < refCap) refList[pz] = row;
            }
        }
    }
    lsum += __shfl_xor(lsum, 32);
    if (lane == 0) atomicAdd(lossAcc, lsum);

    __syncthreads();

    // ---- gather quantized rows: 2 lanes per row, 256 B each ----
    {
        int rl = lane >> 1;
        int best = ldsIdx[wid * 32 + rl];
        const float4* src = (const float4*)(E + (size_t)best * DD + (lane & 1) * 64);
        float4* dst = (float4*)(outZ + (size_t)(rb + rl) * DD + (lane & 1) * 64);
        #pragma unroll
        for (int q = 0; q < 16; ++q) dst[q] = src[q];
    }
}

// ---- fp64 exact re-resolve of flagged rows ----
__global__ void vq_refine(const float* __restrict__ X, const float* __restrict__ E,
                          const float* __restrict__ ema,
                          float* __restrict__ outZ, float* __restrict__ outIdx,
                          double* __restrict__ lossAcc,
                          const int* __restrict__ refCount,
                          const int* __restrict__ refList, int refCap)
{
    __shared__ float xs[DD];
    __shared__ double rb[256];
    __shared__ int    ri[256];
    __shared__ int    s_new, s_old;
    const int tid = threadIdx.x;
    int total = *refCount;
    if (total > refCap) total = refCap;

    for (int it = blockIdx.x; it < total; it += gridDim.x) {
        int row = refList[it];
        __syncthreads();
        if (tid < DD) xs[tid] = X[(size_t)row * DD + tid];
        __syncthreads();

        double lb = 1e300; int li = KTOT;
        #pragma unroll
        for (int j = 0; j < KTOT / 256; ++j) {
            int k = tid + j * 256;
            const float* e = E + (size_t)k * DD;
            double s = 0.0;
            for (int d = 0; d < DD; ++d) {
                double t = (double)xs[d] - (double)e[d];
                s = fma(t, t, s);
            }
            s *= (double)ema[k];
            if (s < lb) { lb = s; li = k; }   // ascending k -> first-min kept
        }
        rb[tid] = lb; ri[tid] = li;
        __syncthreads();
        for (int st = 128; st > 0; st >>= 1) {
            if (tid < st) {
                double ob = rb[tid + st]; int oi = ri[tid + st];
                if (ob < rb[tid] || (ob == rb[tid] && oi < ri[tid])) { rb[tid] = ob; ri[tid] = oi; }
            }
            __syncthreads();
        }
        if (tid == 0) {
            int ni = ri[0];
            int oi = (int)outIdx[row];
            s_new = ni; s_old = oi;
            if (ni != oi) {
                const float* en = E + (size_t)ni * DD;
                const float* eo = E + (size_t)oi * DD;
                double dl = 0.0;
                for (int d = 0; d < DD; ++d) {
                    double dn  = (double)en[d] - (double)xs[d];
                    double dod = (double)eo[d] - (double)xs[d];
                    dl += dn * dn - dod * dod;
                }
                atomicAdd(lossAcc, dl);
                outIdx[row] = (float)ni;
            }
        }
        __syncthreads();
        if (s_new != s_old && tid < DD)
            outZ[(size_t)row * DD + tid] = E[(size_t)s_new * DD + tid];
    }
}

__global__ void vq_finalize(const double* __restrict__ lossAcc, float* __restrict__ outLoss) {
    *outLoss = (float)(0.25 * (*lossAcc) / ((double)BTOT * (double)DD));
}

extern "C" void kernel_launch(void* const* d_in, const int* in_sizes, int n_in,
                              void* d_out, int out_size, void* d_ws, size_t ws_size,
                              hipStream_t stream)
{
    const float* X   = (const float*)d_in[0];
    const float* E   = (const float*)d_in[1];
    const float* ema = (const float*)d_in[2];

    float* out     = (float*)d_out;
    float* outZ    = out;
    float* outLoss = out + (size_t)BTOT * DD;
    float* outIdx  = outLoss + 1;

    char* ws = (char*)d_ws;
    double* lossAcc = (double*)ws;                       // [0,8)
    int* refCount   = (int*)(ws + 8);                    // [8,12)
    float* alpha    = (float*)(ws + 16);                 // 4 KB
    float* beta     = (float*)(ws + 16 + 4096);          // 4 KB
    unsigned short* Eh = (unsigned short*)(ws + 8208);   // 256 KB (16B aligned)
    unsigned short* El = (unsigned short*)(ws + 270352); // 256 KB (16B aligned)
    int* refList    = (int*)(ws + 532496);
    long cap = ((long)ws_size - 532496) / 4;
    if (cap < 0) cap = 0;
    if (cap > BTOT) cap = BTOT;

    hipMemsetAsync(d_ws, 0, 16, stream);
    vq_prep<<<dim3(KTOT / 4), dim3(256), 0, stream>>>(
        E, ema, (unsigned*)Eh, (unsigned*)El, alpha, beta);
    vq_mfma<<<dim3(BTOT / 128), dim3(256), 0, stream>>>(
        X, E, Eh, El, alpha, beta, outZ, outIdx, lossAcc, refCount, refList, (int)cap);
    vq_refine<<<dim3(256), dim3(256), 0, stream>>>(
        X, E, ema, outZ, outIdx, lossAcc, refCount, refList, (int)cap);
    vq_finalize<<<dim3(1), dim3(1), 0, stream>>>(lossAcc, outLoss);
}